// Round 11
// baseline (52.849 us; speedup 1.0000x reference)
//
#include <hip/hip_runtime.h>
#include <stdint.h>

#define NSTEP 32
// DIM = 62 monomials of degree 1..5 over (x0,x1); collapsed per (step,stage)
// into 30 gradient coefficients, packed as f16 pairs (lo=G0[k], hi=G1[k]):
//   G0 = dP/dx0 chain (triangular rows by e0, widths 5,4,3,2,1; inner Horner in x1)
//   G1 = dP/dx1 chain (rows by e1; inner Horner in x0) — index-symmetric.
// GLOBAL table: stage t (t = step*4+which) occupies dwords [t*16 .. t*16+15]
// (15 data + 1 pad) -> one s_load_dwordx16 per stage, 8 KB total (K$-resident).
// Main loop: coefficients live in SGPRs (scalar pipe, zero per-lane
// replication, zero LDS); v_pk_fma_f16 consumes them as its 1 allowed SGPR
// source. Single-outstanding SMEM double-buffer (SMEM returns out-of-order,
// so only lgkmcnt(0) waits are meaningful).

typedef _Float16 h2  __attribute__((ext_vector_type(2)));
typedef uint32_t v16u __attribute__((ext_vector_type(16)));

__device__ __forceinline__ h2 toh2(uint32_t w) { return __builtin_bit_cast(h2, w); }

// issue one stage load into a 16-SGPR tuple; wait + scheduling fence (rule #18)
#define SLOAD(dst, addr) \
    asm volatile("s_load_dwordx16 %0, %1, 0x0" : "=s"(dst) : "s"(addr))
#define SWAIT() do { asm volatile("s_waitcnt lgkmcnt(0)" ::: "memory"); \
                     __builtin_amdgcn_sched_barrier(0); } while (0)

// ---------------------------------------------------------------------------
__global__ void prep_kernel(const float* __restrict__ Aw, const float* __restrict__ Bw,
                            const float* __restrict__ Cw, const float* __restrict__ Dw,
                            uint32_t* __restrict__ G) {
    int t = blockIdx.x * blockDim.x + threadIdx.x;
    if (t >= NSTEP * 4) return;
    int stepi = t >> 2, which = t & 3;
    const float* w;
    switch (which) { case 0: w = Aw; break; case 1: w = Bw; break;
                     case 2: w = Cw; break; default: w = Dw; }
    w += stepi * 62;

    float c[6][6];
#pragma unroll
    for (int a = 0; a < 6; ++a)
#pragma unroll
        for (int b = 0; b < 6; ++b) c[a][b] = 0.f;
    // degree-d flat index f: bits of f are monomial indices; popcount = power of x1
#pragma unroll
    for (int d = 1; d <= 5; ++d)
#pragma unroll
        for (int f = 0; f < (1 << d); ++f) {
            int b = __popc(f);
            c[d - b][b] += w[(1 << d) - 2 + f];
        }

    float g0[15], g1[15];
    int k = 0;
#pragma unroll
    for (int e0 = 0; e0 <= 4; ++e0)
#pragma unroll
        for (int e1 = 0; e1 + e0 <= 4; ++e1)
            g0[k++] = (float)(e0 + 1) * c[e0 + 1][e1];
    k = 0;
#pragma unroll
    for (int e1 = 0; e1 <= 4; ++e1)
#pragma unroll
        for (int e0 = 0; e0 + e1 <= 4; ++e0)
            g1[k++] = (float)(e1 + 1) * c[e0][e1 + 1];

    uint32_t* dst = G + t * 16;
#pragma unroll
    for (int i = 0; i < 15; ++i) {
        h2 h; h.x = (_Float16)g0[i]; h.y = (_Float16)g1[i];
        dst[i] = __builtin_bit_cast(uint32_t, h);
    }
    dst[15] = 0u;
}

// ---------------------------------------------------------------------------
__device__ __forceinline__ void mkpair(float x0, float x1, h2& xm, h2& xo) {
    _Float16 a = (_Float16)x0, b = (_Float16)x1;
    xm.x = b; xm.y = a;   // inner: d0 by x1 (lo), d1 by x0 (hi)
    xo.x = a; xo.y = b;   // outer: d0 by x0 (lo), d1 by x1 (hi)
}

// packed dual-Horner from SGPR-resident coefficients: 14 pk_fma + 2 cvt
__device__ __forceinline__ void pgradv(v16u g, h2 xm, h2 xo, float& d0, float& d1) {
    h2 r0 = toh2(g[4]);
    r0 = r0 * xm + toh2(g[3]);
    r0 = r0 * xm + toh2(g[2]);
    r0 = r0 * xm + toh2(g[1]);
    r0 = r0 * xm + toh2(g[0]);
    h2 r1 = toh2(g[8]);
    r1 = r1 * xm + toh2(g[7]);
    r1 = r1 * xm + toh2(g[6]);
    r1 = r1 * xm + toh2(g[5]);
    h2 r2 = toh2(g[11]);
    r2 = r2 * xm + toh2(g[10]);
    r2 = r2 * xm + toh2(g[9]);
    h2 r3 = toh2(g[13]);
    r3 = r3 * xm + toh2(g[12]);
    h2 acc = toh2(g[14]);
    acc = acc * xo + r3;
    acc = acc * xo + r2;
    acc = acc * xo + r1;
    acc = acc * xo + r0;
    d0 = (float)acc.x;
    d1 = (float)acc.y;
}

__global__ void __launch_bounds__(256, 1)
sympl_main(const float* __restrict__ zin, const uint32_t* __restrict__ Gp,
           const int* __restrict__ nsp, float* __restrict__ zout, int batch) {
    int idx = blockIdx.x * 256 + threadIdx.x;
    bool active = idx < batch;

    float4 zv = make_float4(0.f, 0.f, 0.f, 0.f);
    if (active) zv = reinterpret_cast<const float4*>(zin)[idx];
    float dt  = 1.0f / (32.0f * (float)nsp[0]);
    float hdt = 0.5f * dt;

    float q0 = zv.x, q1 = zv.y, p0 = zv.z, p1 = zv.w;

    v16u c0, c1;
    SLOAD(c0, Gp);                 // step 0 stage A
    SWAIT();

#pragma unroll 1
    for (int s = 0; s < NSTEP; ++s) {
        const uint32_t* b = Gp + s * 64;

        // ---- stage A (from c0); prefetch B -> c1 ----
        SLOAD(c1, b + 16);
        h2 xm, xo; mkpair(p0, p1, xm, xo);
        float dA0, dA1; pgradv(c0, xm, xo, dA0, dA1);
        q0 = fmaf(dA0, hdt, q0); q1 = fmaf(dA1, hdt, q1);
        SWAIT();

        // ---- stage B (from c1); prefetch C -> c0 ----
        SLOAD(c0, b + 32);
        mkpair(q0, q1, xm, xo);
        float dB0, dB1; pgradv(c1, xm, xo, dB0, dB1);
        p0 = fmaf(-dB0, dt, p0); p1 = fmaf(-dB1, dt, p1);
        q0 = fmaf(dA0, hdt, q0); q1 = fmaf(dA1, hdt, q1);
        SWAIT();

        float u0 = q1, u1 = p0, v0 = q0, v1 = p1;

        // ---- stage C (from c0); prefetch D -> c1 ----
        SLOAD(c1, b + 48);
        mkpair(v0, v1, xm, xo);
        float dC0, dC1; pgradv(c0, xm, xo, dC0, dC1);
        u0 = fmaf(dC1, hdt, u0); u1 = fmaf(-dC0, hdt, u1);
        SWAIT();

        // ---- stage D (from c1); prefetch next step's A -> c0 ----
        const uint32_t* an = (s + 1 < NSTEP) ? b + 64 : Gp;
        SLOAD(c0, an);
        mkpair(u0, u1, xm, xo);
        float dD0, dD1; pgradv(c1, xm, xo, dD0, dD1);
        v0 = fmaf(dD1, dt, v0); v1 = fmaf(-dD0, dt, v1);
        u0 = fmaf(dC1, hdt, u0); u1 = fmaf(-dC0, hdt, u1);
        SWAIT();

        q0 = v0; q1 = u0; p0 = u1; p1 = v1;   // z = [v0, u0, u1, v1]
    }

    if (active) {
        float4 o; o.x = q0; o.y = q1; o.z = p0; o.w = p1;
        reinterpret_cast<float4*>(zout)[idx] = o;
    }
}

extern "C" void kernel_launch(void* const* d_in, const int* in_sizes, int n_in,
                              void* d_out, int out_size, void* d_ws, size_t ws_size,
                              hipStream_t stream) {
    const float* z  = (const float*)d_in[0];
    const float* Aw = (const float*)d_in[1];
    const float* Bw = (const float*)d_in[2];
    const float* Cw = (const float*)d_in[3];
    const float* Dw = (const float*)d_in[4];
    const int*   ns = (const int*)d_in[5];
    uint32_t* G = (uint32_t*)d_ws;   // 128 stages x 16 dwords = 8 KB

    prep_kernel<<<1, 128, 0, stream>>>(Aw, Bw, Cw, Dw, G);

    int batch = in_sizes[0] / 4;
    int threads = 256;
    int blocks = (batch + threads - 1) / threads;
    sympl_main<<<blocks, threads, 0, stream>>>(z, G, ns, (float*)d_out, batch);
}

// Round 13
// 21.731 us; speedup vs baseline: 2.4319x; 2.4319x over previous
//
#include <hip/hip_runtime.h>
#include <stdint.h>

#define NSTEP 32
// DIM = 62 monomials of degree 1..5 over (x0,x1); collapsed to 30 gradient
// coefficients per (step, stage), PACKED as f16 pairs:
//   word k (k=0..14) = ( G0[k] , G1[k] ) = (lo,hi), where
//   G0 = dP/dx0 chain (triangular rows by e0, widths 5,4,3,2,1; inner Horner in x1)
//   G1 = dP/dx1 chain (rows by e1; inner Horner in x0) — index-symmetric to G0.
// BOTH chains evaluate in ONE packed v_pk_fma_f16 stream: inner multiplier
// pair xm=(x1,x0), outer xo=(x0,x1); 14 pk_fma + 2 cvt per stage.
// LDS table: sGp[step*64 + stage*15 + k] (uint32) -> 15 ds_read_b128/step/wave.
// PREP: weights staged into LDS via coalesced float4 copy first (R10's direct
// global reads were 64-cacheline-divergent per instruction), then collapsed.

typedef _Float16 h2 __attribute__((ext_vector_type(2)));

__device__ __forceinline__ h2 toh2(uint32_t w) { return __builtin_bit_cast(h2, w); }

__device__ __forceinline__ void loadstep(const uint32_t* __restrict__ sg, uint32_t (&R)[60]) {
#pragma unroll
    for (int i = 0; i < 15; ++i) {
        uint4 v = *reinterpret_cast<const uint4*>(sg + i * 4);
        R[i * 4 + 0] = v.x; R[i * 4 + 1] = v.y;
        R[i * 4 + 2] = v.z; R[i * 4 + 3] = v.w;
    }
}

// packed dual-Horner: d0 over (inner x1, outer x0) in lo; d1 over (inner x0,
// outer x1) in hi. 14 pk_fma (mul+add contracted) + 2 cvt.
template <int B>
__device__ __forceinline__ void pgrad(const uint32_t (&g)[60], h2 xm, h2 xo,
                                      float& d0, float& d1) {
    h2 r0 = toh2(g[B + 4]);
    r0 = r0 * xm + toh2(g[B + 3]);
    r0 = r0 * xm + toh2(g[B + 2]);
    r0 = r0 * xm + toh2(g[B + 1]);
    r0 = r0 * xm + toh2(g[B + 0]);
    h2 r1 = toh2(g[B + 8]);
    r1 = r1 * xm + toh2(g[B + 7]);
    r1 = r1 * xm + toh2(g[B + 6]);
    r1 = r1 * xm + toh2(g[B + 5]);
    h2 r2 = toh2(g[B + 11]);
    r2 = r2 * xm + toh2(g[B + 10]);
    r2 = r2 * xm + toh2(g[B + 9]);
    h2 r3 = toh2(g[B + 13]);
    r3 = r3 * xm + toh2(g[B + 12]);
    h2 acc = toh2(g[B + 14]);
    acc = acc * xo + r3;
    acc = acc * xo + r2;
    acc = acc * xo + r1;
    acc = acc * xo + r0;
    d0 = (float)acc.x;
    d1 = (float)acc.y;
}

// 2 ops: v_cvt_pkrtz_f16_f32 packs (lo,hi) directly
__device__ __forceinline__ void mkpair(float x0, float x1, h2& xm, h2& xo) {
    xo = __builtin_bit_cast(h2, __builtin_amdgcn_cvt_pkrtz(x0, x1));   // (x0, x1)
    xm = __builtin_bit_cast(h2, __builtin_amdgcn_cvt_pkrtz(x1, x0));   // (x1, x0)
}

__device__ __forceinline__ void dostep(const uint32_t (&g)[60], float& q0, float& q1,
                                       float& p0, float& p1, float dt, float hdt) {
    h2 xm, xo;

    mkpair(p0, p1, xm, xo);
    float dA0, dA1; pgrad<0>(g, xm, xo, dA0, dA1);
    q0 = fmaf(dA0, hdt, q0); q1 = fmaf(dA1, hdt, q1);

    mkpair(q0, q1, xm, xo);
    float dB0, dB1; pgrad<15>(g, xm, xo, dB0, dB1);
    p0 = fmaf(-dB0, dt, p0); p1 = fmaf(-dB1, dt, p1);
    q0 = fmaf(dA0, hdt, q0); q1 = fmaf(dA1, hdt, q1);

    float u0 = q1, u1 = p0, v0 = q0, v1 = p1;

    mkpair(v0, v1, xm, xo);
    float dC0, dC1; pgrad<30>(g, xm, xo, dC0, dC1);
    u0 = fmaf(dC1, hdt, u0); u1 = fmaf(-dC0, hdt, u1);

    mkpair(u0, u1, xm, xo);
    float dD0, dD1; pgrad<45>(g, xm, xo, dD0, dD1);
    v0 = fmaf(dD1, dt, v0); v1 = fmaf(-dD0, dt, v1);
    u0 = fmaf(dC1, hdt, u0); u1 = fmaf(-dC0, hdt, u1);

    q0 = v0; q1 = u0; p0 = u1; p1 = v1;   // z = [v0, u0, u1, v1]
}

#define WFLOATS (NSTEP * 62)   // 1984 floats per weight array

__global__ void __launch_bounds__(256, 1)
sympl_fused(const float* __restrict__ zin,
            const float* __restrict__ Aw, const float* __restrict__ Bw,
            const float* __restrict__ Cw, const float* __restrict__ Dw,
            const int* __restrict__ nsp,
            float* __restrict__ zout, int batch) {
    __shared__ float    sW[4 * WFLOATS];   // staged weights (31 KB)
    __shared__ uint32_t sGp[NSTEP * 64];   // packed table (8 KB)

    int lt = threadIdx.x;
    int idx = blockIdx.x * 256 + lt;
    bool active = idx < batch;

    // issue the z load immediately (independent of prep)
    float4 zv = make_float4(0.f, 0.f, 0.f, 0.f);
    if (active) zv = reinterpret_cast<const float4*>(zin)[idx];
    float dt  = 1.0f / (32.0f * (float)nsp[0]);
    float hdt = 0.5f * dt;

    // ---- coalesced weight staging: 4 arrays x 496 float4 ----
    {
        const float* srcs[4] = {Aw, Bw, Cw, Dw};
#pragma unroll
        for (int a = 0; a < 4; ++a) {
            const float4* s4 = reinterpret_cast<const float4*>(srcs[a]);
            float4* d4 = reinterpret_cast<float4*>(sW + a * WFLOATS);
            // 496 float4 per array, 256 threads -> 2 strided rounds
            if (lt < 248) d4[lt] = s4[lt];
            int j = lt + 248;
            if (j < 496) d4[j] = s4[j];
        }
    }
    __syncthreads();

    // ---- per-block prep: 128 (step, stage) collapse tasks from LDS ----
    if (lt < NSTEP * 4) {
        int stepi = lt >> 2, which = lt & 3;
        const float* w = sW + which * WFLOATS + stepi * 62;

        float c[6][6];
#pragma unroll
        for (int a = 0; a < 6; ++a)
#pragma unroll
            for (int b = 0; b < 6; ++b) c[a][b] = 0.f;
        // degree-d flat index f: bits of f are monomial indices; popcount = power of x1
#pragma unroll
        for (int d = 1; d <= 5; ++d)
#pragma unroll
            for (int f = 0; f < (1 << d); ++f) {
                int b = __popc(f);
                c[d - b][b] += w[(1 << d) - 2 + f];
            }

        float g0[15], g1[15];
        int k = 0;
#pragma unroll
        for (int e0 = 0; e0 <= 4; ++e0)
#pragma unroll
            for (int e1 = 0; e1 + e0 <= 4; ++e1)
                g0[k++] = (float)(e0 + 1) * c[e0 + 1][e1];
        k = 0;
#pragma unroll
        for (int e1 = 0; e1 <= 4; ++e1)
#pragma unroll
            for (int e0 = 0; e0 + e1 <= 4; ++e0)
                g1[k++] = (float)(e1 + 1) * c[e0][e1 + 1];

        uint32_t* dst = sGp + stepi * 64 + which * 15;
#pragma unroll
        for (int i = 0; i < 15; ++i) {
            h2 h; h.x = (_Float16)g0[i]; h.y = (_Float16)g1[i];
            dst[i] = __builtin_bit_cast(uint32_t, h);
        }
        if (which == 0) { sGp[stepi * 64 + 60] = 0u; sGp[stepi * 64 + 61] = 0u;
                          sGp[stepi * 64 + 62] = 0u; sGp[stepi * 64 + 63] = 0u; }
    }
    __syncthreads();

    float q0 = zv.x, q1 = zv.y, p0 = zv.z, p1 = zv.w;

    // ---- main loop: full-step register double buffer, unroll x2 ----
    uint32_t bufX[60], bufY[60];
    loadstep(sGp, bufX);                      // step 0

#pragma unroll 1
    for (int it = 0; it < NSTEP / 2; ++it) {
        int s = 2 * it;
        loadstep(sGp + (s + 1) * 64, bufY);
        dostep(bufX, q0, q1, p0, p1, dt, hdt);
        int sn = (s + 2 < NSTEP) ? s + 2 : NSTEP - 1;
        loadstep(sGp + sn * 64, bufX);
        dostep(bufY, q0, q1, p0, p1, dt, hdt);
    }

    if (active) {
        float4 o; o.x = q0; o.y = q1; o.z = p0; o.w = p1;
        reinterpret_cast<float4*>(zout)[idx] = o;
    }
}

extern "C" void kernel_launch(void* const* d_in, const int* in_sizes, int n_in,
                              void* d_out, int out_size, void* d_ws, size_t ws_size,
                              hipStream_t stream) {
    const float* z  = (const float*)d_in[0];
    const float* Aw = (const float*)d_in[1];
    const float* Bw = (const float*)d_in[2];
    const float* Cw = (const float*)d_in[3];
    const float* Dw = (const float*)d_in[4];
    const int*   ns = (const int*)d_in[5];

    int batch = in_sizes[0] / 4;
    int threads = 256;
    int blocks = (batch + threads - 1) / threads;
    sympl_fused<<<blocks, threads, 0, stream>>>(z, Aw, Bw, Cw, Dw, ns,
                                                (float*)d_out, batch);
}

// Round 14
// 15.464 us; speedup vs baseline: 3.4176x; 1.4053x over previous
//
#include <hip/hip_runtime.h>
#include <stdint.h>

#define NSTEP 32
// DIM = 62 monomials of degree 1..5 over (x0,x1); collapsed to 30 gradient
// coefficients per (step, stage), PACKED as f16 pairs:
//   word k (k=0..14) = ( G0[k] , G1[k] ) = (lo,hi), where
//   G0 = dP/dx0 chain (triangular rows by e0, widths 5,4,3,2,1; inner Horner in x1)
//   G1 = dP/dx1 chain (rows by e1; inner Horner in x0) — index-symmetric to G0.
// BOTH chains evaluate in ONE packed v_pk_fma_f16 stream: inner multiplier
// pair xm=(x1,x0), outer xo=(x0,x1); 14 pk_fma + 2 cvt per stage.
// LDS table: sGp[step*64 + stage*15 + k] (uint32) -> 15 ds_read_b128/step/wave.
// PREP (R14): direct-from-global (R13's LDS staging regressed), but via
// float2 loads — rows are 8B-aligned and every degree block starts at an even
// offset, halving divergent-load instructions and line-touches.

typedef _Float16 h2 __attribute__((ext_vector_type(2)));

__device__ __forceinline__ h2 toh2(uint32_t w) { return __builtin_bit_cast(h2, w); }

__device__ __forceinline__ void loadstep(const uint32_t* __restrict__ sg, uint32_t (&R)[60]) {
#pragma unroll
    for (int i = 0; i < 15; ++i) {
        uint4 v = *reinterpret_cast<const uint4*>(sg + i * 4);
        R[i * 4 + 0] = v.x; R[i * 4 + 1] = v.y;
        R[i * 4 + 2] = v.z; R[i * 4 + 3] = v.w;
    }
}

// packed dual-Horner: d0 over (inner x1, outer x0) in lo; d1 over (inner x0,
// outer x1) in hi. 14 pk_fma (mul+add contracted) + 2 cvt.
template <int B>
__device__ __forceinline__ void pgrad(const uint32_t (&g)[60], h2 xm, h2 xo,
                                      float& d0, float& d1) {
    h2 r0 = toh2(g[B + 4]);
    r0 = r0 * xm + toh2(g[B + 3]);
    r0 = r0 * xm + toh2(g[B + 2]);
    r0 = r0 * xm + toh2(g[B + 1]);
    r0 = r0 * xm + toh2(g[B + 0]);
    h2 r1 = toh2(g[B + 8]);
    r1 = r1 * xm + toh2(g[B + 7]);
    r1 = r1 * xm + toh2(g[B + 6]);
    r1 = r1 * xm + toh2(g[B + 5]);
    h2 r2 = toh2(g[B + 11]);
    r2 = r2 * xm + toh2(g[B + 10]);
    r2 = r2 * xm + toh2(g[B + 9]);
    h2 r3 = toh2(g[B + 13]);
    r3 = r3 * xm + toh2(g[B + 12]);
    h2 acc = toh2(g[B + 14]);
    acc = acc * xo + r3;
    acc = acc * xo + r2;
    acc = acc * xo + r1;
    acc = acc * xo + r0;
    d0 = (float)acc.x;
    d1 = (float)acc.y;
}

// 2 ops: v_cvt_pkrtz_f16_f32 packs (lo,hi) directly
__device__ __forceinline__ void mkpair(float x0, float x1, h2& xm, h2& xo) {
    xo = __builtin_bit_cast(h2, __builtin_amdgcn_cvt_pkrtz(x0, x1));   // (x0, x1)
    xm = __builtin_bit_cast(h2, __builtin_amdgcn_cvt_pkrtz(x1, x0));   // (x1, x0)
}

__device__ __forceinline__ void dostep(const uint32_t (&g)[60], float& q0, float& q1,
                                       float& p0, float& p1, float dt, float hdt) {
    h2 xm, xo;

    mkpair(p0, p1, xm, xo);
    float dA0, dA1; pgrad<0>(g, xm, xo, dA0, dA1);
    q0 = fmaf(dA0, hdt, q0); q1 = fmaf(dA1, hdt, q1);

    mkpair(q0, q1, xm, xo);
    float dB0, dB1; pgrad<15>(g, xm, xo, dB0, dB1);
    p0 = fmaf(-dB0, dt, p0); p1 = fmaf(-dB1, dt, p1);
    q0 = fmaf(dA0, hdt, q0); q1 = fmaf(dA1, hdt, q1);

    float u0 = q1, u1 = p0, v0 = q0, v1 = p1;

    mkpair(v0, v1, xm, xo);
    float dC0, dC1; pgrad<30>(g, xm, xo, dC0, dC1);
    u0 = fmaf(dC1, hdt, u0); u1 = fmaf(-dC0, hdt, u1);

    mkpair(u0, u1, xm, xo);
    float dD0, dD1; pgrad<45>(g, xm, xo, dD0, dD1);
    v0 = fmaf(dD1, dt, v0); v1 = fmaf(-dD0, dt, v1);
    u0 = fmaf(dC1, hdt, u0); u1 = fmaf(-dC0, hdt, u1);

    q0 = v0; q1 = u0; p0 = u1; p1 = v1;   // z = [v0, u0, u1, v1]
}

__global__ void __launch_bounds__(256, 1)
sympl_fused(const float* __restrict__ zin,
            const float* __restrict__ Aw, const float* __restrict__ Bw,
            const float* __restrict__ Cw, const float* __restrict__ Dw,
            const int* __restrict__ nsp,
            float* __restrict__ zout, int batch) {
    __shared__ uint32_t sGp[NSTEP * 64];

    int lt = threadIdx.x;
    int idx = blockIdx.x * 256 + lt;
    bool active = idx < batch;

    // issue the z load immediately (independent of prep)
    float4 zv = make_float4(0.f, 0.f, 0.f, 0.f);
    if (active) zv = reinterpret_cast<const float4*>(zin)[idx];
    float dt  = 1.0f / (32.0f * (float)nsp[0]);
    float hdt = 0.5f * dt;

    // ---- per-block redundant prep: 128 (step, stage) collapse tasks ----
    if (lt < NSTEP * 4) {
        int stepi = lt >> 2, which = lt & 3;
        const float* w;
        switch (which) { case 0: w = Aw; break; case 1: w = Bw; break;
                         case 2: w = Cw; break; default: w = Dw; }
        w += stepi * 62;                       // even offset -> 8B aligned
        const float2* w2 = reinterpret_cast<const float2*>(w);

        float c[6][6];
#pragma unroll
        for (int a = 0; a < 6; ++a)
#pragma unroll
            for (int b = 0; b < 6; ++b) c[a][b] = 0.f;
        // degree-d flat index f: bits of f are monomial indices; popcount =
        // power of x1. f even -> popc(f+1) = popc(f)+1.
#pragma unroll
        for (int d = 1; d <= 5; ++d) {
            int base2 = ((1 << d) - 2) >> 1;
#pragma unroll
            for (int fp = 0; fp < (1 << d) / 2; ++fp) {
                float2 v = w2[base2 + fp];
                int b = __popc(2 * fp);
                c[d - b][b]         += v.x;
                c[d - b - 1][b + 1] += v.y;
            }
        }

        float g0[15], g1[15];
        int k = 0;
#pragma unroll
        for (int e0 = 0; e0 <= 4; ++e0)
#pragma unroll
            for (int e1 = 0; e1 + e0 <= 4; ++e1)
                g0[k++] = (float)(e0 + 1) * c[e0 + 1][e1];
        k = 0;
#pragma unroll
        for (int e1 = 0; e1 <= 4; ++e1)
#pragma unroll
            for (int e0 = 0; e0 + e1 <= 4; ++e0)
                g1[k++] = (float)(e1 + 1) * c[e0][e1 + 1];

        uint32_t* dst = sGp + stepi * 64 + which * 15;
#pragma unroll
        for (int i = 0; i < 15; ++i) {
            h2 h; h.x = (_Float16)g0[i]; h.y = (_Float16)g1[i];
            dst[i] = __builtin_bit_cast(uint32_t, h);
        }
        if (which == 0) { sGp[stepi * 64 + 60] = 0u; sGp[stepi * 64 + 61] = 0u;
                          sGp[stepi * 64 + 62] = 0u; sGp[stepi * 64 + 63] = 0u; }
    }
    __syncthreads();

    float q0 = zv.x, q1 = zv.y, p0 = zv.z, p1 = zv.w;

    // ---- main loop: full-step register double buffer, unroll x2 ----
    uint32_t bufX[60], bufY[60];
    loadstep(sGp, bufX);                      // step 0

#pragma unroll 1
    for (int it = 0; it < NSTEP / 2; ++it) {
        int s = 2 * it;
        loadstep(sGp + (s + 1) * 64, bufY);
        dostep(bufX, q0, q1, p0, p1, dt, hdt);
        int sn = (s + 2 < NSTEP) ? s + 2 : NSTEP - 1;
        loadstep(sGp + sn * 64, bufX);
        dostep(bufY, q0, q1, p0, p1, dt, hdt);
    }

    if (active) {
        float4 o; o.x = q0; o.y = q1; o.z = p0; o.w = p1;
        reinterpret_cast<float4*>(zout)[idx] = o;
    }
}

extern "C" void kernel_launch(void* const* d_in, const int* in_sizes, int n_in,
                              void* d_out, int out_size, void* d_ws, size_t ws_size,
                              hipStream_t stream) {
    const float* z  = (const float*)d_in[0];
    const float* Aw = (const float*)d_in[1];
    const float* Bw = (const float*)d_in[2];
    const float* Cw = (const float*)d_in[3];
    const float* Dw = (const float*)d_in[4];
    const int*   ns = (const int*)d_in[5];

    int batch = in_sizes[0] / 4;
    int threads = 256;
    int blocks = (batch + threads - 1) / threads;
    sympl_fused<<<blocks, threads, 0, stream>>>(z, Aw, Bw, Cw, Dw, ns,
                                                (float*)d_out, batch);
}